// Round 6
// baseline (359.010 us; speedup 1.0000x reference)
//
#include <hip/hip_runtime.h>

// Problem constants (from setup_inputs): B=4, H=384, W=512, C=64, fp32.
constexpr int B = 4, H = 384, W = 512, C = 64;
constexpr int HW = H * W;                        // 196608
constexpr int C4 = C / 4;                        // 16 float4 chunks per pixel
constexpr int BLOCKS_PER_IMG = HW * C4 / 256;    // 12288
constexpr int TOTAL_BLOCKS = B * BLOCKS_PER_IMG; // 49152
constexpr int NXCD = 8;
constexpr int CHUNK = TOTAL_BLOCKS / NXCD;       // 6144 blocks = 192 rows per XCD
constexpr int PF_ROWS = 40;   // prefetch distance in rows (> max|flow| ~26 + pipe depth)

// Native clang vector types (required by __builtin_nontemporal_store).
typedef float f32x4 __attribute__((ext_vector_type(4)));
typedef float f32x2 __attribute__((ext_vector_type(2)));

// 16 consecutive threads per output pixel (one float4 of channels each): every
// bilinear tap is a contiguous 256 B row segment -> coalesced.
//
// XCD slab swizzle + marching prefetch (the two are complementary):
//  - blockIdx round-robins across the 8 XCDs, so swizzle maps each XCD to a
//    CONTIGUOUS 192-row slab of the flattened (B*H)-row sequence. The bilinear
//    reuse window (flow spread ~±26 rows) then lives in that XCD's own 4 MB L2
//    (edge leakage only ~14%).
//  - each block densely prefetches the row PF_ROWS ahead of its slab's front;
//    with the swizzle, the prefetching block and the eventual consumers are on
//    the SAME XCD, so the prefetch fills the right L2 (in r5, without swizzle,
//    consumers were spread over all 8 XCDs and the prefetch was neutral).
__global__ __launch_bounds__(256) void warp_kernel(
    const f32x2* __restrict__ flow,    // (B,H,W,2)
    const f32x4* __restrict__ feat,    // (B,H,W,C)
    const float* __restrict__ mask,    // (H,W)
    f32x4* __restrict__ out)           // (B,H,W,C)
{
    int bx   = blockIdx.x;
    int sbx  = (bx & (NXCD - 1)) * CHUNK + (bx >> 3);  // bijective (49152 % 8 == 0)
    int gid  = sbx * 256 + threadIdx.x;                // over B * HW * C4
    int c4   = gid & (C4 - 1);
    int gpix = gid >> 4;          // 0 .. B*HW : flattened (b, y, x)
    int xg   = gpix & (W - 1);    // W = 512 (pow2)
    int grow = gpix >> 9;         // 0 .. B*H  : flattened (b, y)
    int b    = grow / H;          // const div -> magic multiply
    int yg   = grow - b * H;
    int hw   = yg * W + xg;

    // Dependent loads first (flow, mask), then the fire-and-forget dense
    // prefetch; vmcnt is ordered, so waiting on flow keeps the prefetch
    // in flight.
    f32x2 f = flow[gpix];
    float m = mask[hw];

    f32x4 pf = {};
    int pf_gpix = gpix + PF_ROWS * W;
    if (pf_gpix < B * HW)
        pf = feat[pf_gpix * C4 + c4];

    float xt = (float)xg + f.x;
    float yt = (float)yg + f.y;

    // == (2*xt/(W-1) - 1 + 1) * 0.5 * W, constant-folded to one multiply.
    float x = xt * ((float)W / (float)(W - 1));
    float y = yt * ((float)H / (float)(H - 1));

    // reference clamps the INT coords, then derives weights from clamped values
    int x0 = min(max((int)floorf(x), 0), W - 1);
    int x1 = min(x0 + 1, W - 1);
    int y0 = min(max((int)floorf(y), 0), H - 1);
    int y1 = min(y0 + 1, H - 1);
    float x0f = (float)x0, x1f = (float)x1;
    float y0f = (float)y0, y1f = (float)y1;

    float wa = (x1f - x) * (y1f - y);
    float wb = (x1f - x) * (y - y0f);
    float wc = (x - x0f) * (y1f - y);
    float wd = (x - x0f) * (y - y0f);

    int base = b * HW;
    f32x4 va = feat[(base + y0 * W + x0) * C4 + c4];
    f32x4 vb = feat[(base + y1 * W + x0) * C4 + c4];
    f32x4 vc = feat[(base + y0 * W + x1) * C4 + c4];
    f32x4 vd = feat[(base + y1 * W + x1) * C4 + c4];

    f32x4 r = (wa * va + wb * vb + wc * vc + wd * vd) * m;

    // Keep the prefetch value live without storing it (prevents DCE).
    asm volatile("" :: "v"(pf));

    // Non-temporal: write-once output; don't evict the warmed feature window.
    __builtin_nontemporal_store(r, &out[gpix * C4 + c4]);
}

extern "C" void kernel_launch(void* const* d_in, const int* in_sizes, int n_in,
                              void* d_out, int out_size, void* d_ws, size_t ws_size,
                              hipStream_t stream) {
    const f32x2* flow = (const f32x2*)d_in[0];   // w: (B,H,W,2)
    const f32x4* feat = (const f32x4*)d_in[1];   // feature: (B,H,W,C)
    const float* mask = (const float*)d_in[2];   // mask: (H,W)
    f32x4* out = (f32x4*)d_out;

    dim3 grid(TOTAL_BLOCKS), block(256);
    warp_kernel<<<grid, block, 0, stream>>>(flow, feat, mask, out);
}